// Round 1
// baseline (489.175 us; speedup 1.0000x reference)
//
#include <hip/hip_runtime.h>
#include <cstdint>
#include <cstddef>

// PureCartesianTensorProduct: B=4096, C1=C2=COUT=64, LMAX=2, FEAT=832, 15 paths.
// out[z,c,m] = sum_p sum_ab W_p[c,a,b] * T_p,m[z,a,b], T = geometric contraction.
// MFMA f32_32x32x16_f16: A-operand = W[c][k=a*64+b] (M=c), B-operand = T (N=z),
// T built in registers from per-lane s_t = +-A1[z,a,i_t] and LDS-staged x2 rows.

#define FEAT 832
#define ZT 128

typedef _Float16 half8 __attribute__((ext_vector_type(8)));
typedef _Float16 half4 __attribute__((ext_vector_type(4)));
typedef float floatx16 __attribute__((ext_vector_type(16)));

struct Chunk {
  int wbase;      // p * 64*4096, element offset into f16 weight
  int o1[3];      // absolute x1 feature offset for term t (at a=0)
  int o2[3];      // absolute x2 feature offset for term t (at b=0)
  float sg[3];    // +-1
  int d1, d2, nt; // a-stride (3^L1), b-stride (3^L2), #terms (<=3)
};

__global__ void cvt_w_kernel(const float* __restrict__ w, _Float16* __restrict__ o, int n4) {
  int i = blockIdx.x * 256 + threadIdx.x;
  if (i < n4) {
    const float4 v = ((const float4*)w)[i];
    half4 h = { (_Float16)v.x, (_Float16)v.y, (_Float16)v.z, (_Float16)v.w };
    ((half4*)o)[i] = h;
  }
}

template<int NT>
__device__ __forceinline__ void run_chunk(
    const Chunk C, int zbase, int zg, int zl, int ln31, int hf, int tid,
    const float* __restrict__ x1, const float* __restrict__ x2,
    const _Float16* __restrict__ Wh,
    _Float16 (&X2s)[3][ZT][72], _Float16 (&Ws)[64][72],
    floatx16& acc0, floatx16& acc1)
{
  __syncthreads();  // previous chunk's readers of X2s/Ws are done

  // stage x2 tile: X2s[t][z][b] = x2[z, b-channel, geom j_t], f16
  #pragma unroll
  for (int t = 0; t < NT; ++t) {
    const size_t base2 = (size_t)zbase * FEAT + C.o2[t];
    for (int e = tid; e < ZT * 64; e += 256) {
      const int zz = e >> 6, b = e & 63;
      X2s[t][zz][b] = (_Float16)x2[base2 + (size_t)zz * FEAT + (size_t)b * C.d2];
    }
  }

  const _Float16* __restrict__ Wp = Wh + C.wbase;
  const int wc  = tid >> 3;        // 0..31 (row; also row+32)
  const int wsv = (tid & 7) * 8;   // 0..56, 8 f16 = 16B per thread per row
  const size_t wg0 = ((size_t)wc << 12) + wsv;
  const size_t wg1 = (((size_t)wc + 32) << 12) + wsv;
  const size_t a1base = (size_t)zg * FEAT;

  for (int a = 0; a < 64; ++a) {
    // per-lane A1 scalars for this a (issued before barrier -> latency hidden)
    float av[NT];
    #pragma unroll
    for (int t = 0; t < NT; ++t)
      av[t] = x1[a1base + C.o1[t] + (size_t)a * C.d1] * C.sg[t];

    __syncthreads();  // prev iter done reading Ws; (iter 0: X2s staged)
    {
      const int aoff = a * 64;
      *(half8*)&Ws[wc][wsv]      = *(const half8*)&Wp[wg0 + aoff];
      *(half8*)&Ws[wc + 32][wsv] = *(const half8*)&Wp[wg1 + aoff];
    }
    __syncthreads();

    half8 sv[NT];
    #pragma unroll
    for (int t = 0; t < NT; ++t) {
      const _Float16 h = (_Float16)av[t];
      sv[t] = half8{h, h, h, h, h, h, h, h};
    }

    #pragma unroll
    for (int ks = 0; ks < 4; ++ks) {
      const int ko = ks * 16 + hf * 8;  // b-offset covered by this lane's 8 k-slots
      half8 tacc = sv[0] * *(const half8*)&X2s[0][zl][ko];
      if (NT > 1) tacc += sv[1] * *(const half8*)&X2s[1][zl][ko];
      if (NT > 2) tacc += sv[2] * *(const half8*)&X2s[2][zl][ko];
      const half8 af0 = *(const half8*)&Ws[ln31][ko];
      const half8 af1 = *(const half8*)&Ws[ln31 + 32][ko];
      acc0 = __builtin_amdgcn_mfma_f32_32x32x16_f16(af0, tacc, acc0, 0, 0, 0);
      acc1 = __builtin_amdgcn_mfma_f32_32x32x16_f16(af1, tacc, acc1, 0, 0, 0);
    }
  }
}

__global__ __launch_bounds__(256, 2) void tp_kernel(
    const float* __restrict__ x1, const float* __restrict__ x2,
    const _Float16* __restrict__ Wh, float* __restrict__ out)
{
  __shared__ __align__(16) _Float16 X2s[3][ZT][72]; // 55296 B (b-stride 72: banks + 16B align)
  __shared__ __align__(16) _Float16 Ws[64][72];     //  9216 B
  __shared__ Chunk chs[7];
  __shared__ int nch_s;

  const int tid  = threadIdx.x;
  const int slot = blockIdx.y;           // 0: L0; 1..3: L1 m; 4..12: L2 (u,v)
  const int zbase = blockIdx.x * ZT;
  const int wv   = tid >> 6;
  const int lane = tid & 63;
  const int ln31 = lane & 31;
  const int hf   = lane >> 5;
  const int zl   = wv * 32 + ln31;       // z within tile (B-frag n = lane&31)
  const int zg   = zbase + zl;

  int offO, dO, mO;
  if (slot == 0)      { offO = 0;   dO = 1; mO = 0; }
  else if (slot < 4)  { offO = 64;  dO = 3; mO = slot - 1; }
  else                { offO = 256; dO = 9; mO = slot - 4; }

  if (tid == 0) {
    int n = 0;
    auto add = [&](int p, int L1, int L2,
                   int i0, int i1, int i2, int j0, int j1, int j2,
                   float s0, float s1, float s2, int nt) {
      const int offs[3] = {0, 64, 256};
      const int ds[3]   = {1, 3, 9};
      Chunk c;
      c.wbase = p * (64 * 4096);
      c.o1[0] = offs[L1] + i0; c.o1[1] = offs[L1] + i1; c.o1[2] = offs[L1] + i2;
      c.o2[0] = offs[L2] + j0; c.o2[1] = offs[L2] + j1; c.o2[2] = offs[L2] + j2;
      c.sg[0] = s0; c.sg[1] = s1; c.sg[2] = s2;
      c.d1 = ds[L1]; c.d2 = ds[L2]; c.nt = nt;
      chs[n++] = c;
    };
    if (slot == 0) {
      add(0, 0,0, 0,0,0, 0,0,0, 1,0,0, 1);                  // A0*B0
      add(5, 1,1, 0,1,2, 0,1,2, 1,1,1, 3);                  // sum_e A1[e]B1[e]
      add(13,2,2, 0,1,2, 0,1,2, 1,1,1, 3);                  // sum_g A2[g]B2[g] (3 chunks)
      add(13,2,2, 3,4,5, 3,4,5, 1,1,1, 3);
      add(13,2,2, 6,7,8, 6,7,8, 1,1,1, 3);
    } else if (slot < 4) {
      const int m = slot - 1, p1 = (m+1)%3, p2 = (m+2)%3;
      add(1, 0,1, 0,0,0, m,0,0, 1,0,0, 1);                  // A0*B1[m]
      add(3, 1,0, m,0,0, 0,0,0, 1,0,0, 1);                  // A1[m]*B0
      add(6, 1,1, p1,p2,0, p2,p1,0, 1,-1,0, 2);             // eps(m,x,y)A1[x]B1[y]
      add(7, 1,2, 0,1,2, 3*m,3*m+1,3*m+2, 1,1,1, 3);        // sum_e A1[e]B2[m,e]
      add(10,2,1, 3*m,3*m+1,3*m+2, 0,1,2, 1,1,1, 3);        // sum_e A2[m,e]B1[e]
      add(14,2,2, 3*p1,3*p1+1,3*p1+2, 3*p2,3*p2+1,3*p2+2, 1,1,1, 3);    // +A2[p1,e]B2[p2,e]
      add(14,2,2, 3*p2,3*p2+1,3*p2+2, 3*p1,3*p1+1,3*p1+2, -1,-1,-1, 3); // -A2[p2,e]B2[p1,e]
    } else {
      const int m = slot - 4, u = m/3, v = m%3, q1 = (v+1)%3, q2 = (v+2)%3;
      add(2, 0,2, 0,0,0, m,0,0, 1,0,0, 1);                  // A0*B2[u,v]
      add(4, 1,1, u,0,0, v,0,0, 1,0,0, 1);                  // A1[u]*B1[v]
      add(8, 1,2, q1,q2,0, 3*u+q2,3*u+q1,0, 1,-1,0, 2);     // eps(v,x,y)A1[x]B2[u,y]
      add(9, 2,0, m,0,0, 0,0,0, 1,0,0, 1);                  // A2[u,v]*B0
      add(11,2,1, 3*u+q1,3*u+q2,0, q2,q1,0, 1,-1,0, 2);     // eps(v,e,f)A2[u,e]B1[f]
      add(12,2,2, 3*u,3*u+1,3*u+2, 3*v,3*v+1,3*v+2, 1,1,1, 3); // sum_e A2[u,e]B2[v,e]
    }
    nch_s = n;
  }
  __syncthreads();
  const int nch = nch_s;

  floatx16 acc0, acc1;
  #pragma unroll
  for (int r = 0; r < 16; ++r) { acc0[r] = 0.0f; acc1[r] = 0.0f; }

  for (int ci = 0; ci < nch; ++ci) {
    const Chunk C = chs[ci];  // block-uniform
    if (C.nt == 1)      run_chunk<1>(C, zbase, zg, zl, ln31, hf, tid, x1, x2, Wh, X2s, Ws, acc0, acc1);
    else if (C.nt == 2) run_chunk<2>(C, zbase, zg, zl, ln31, hf, tid, x1, x2, Wh, X2s, Ws, acc0, acc1);
    else                run_chunk<3>(C, zbase, zg, zl, ln31, hf, tid, x1, x2, Wh, X2s, Ws, acc0, acc1);
  }

  // epilogue: C/D layout 32x32: col(z)=lane&31, row(c)=(r&3)+8*(r>>2)+4*(lane>>5)
  float* __restrict__ op = out + (size_t)zg * FEAT + offO + mO;
  #pragma unroll
  for (int r = 0; r < 16; ++r) {
    const int crow = (r & 3) + 8 * (r >> 2) + 4 * hf;
    op[(size_t)crow * dO]        = acc0[r];
    op[(size_t)(crow + 32) * dO] = acc1[r];
  }
}

extern "C" void kernel_launch(void* const* d_in, const int* in_sizes, int n_in,
                              void* d_out, int out_size, void* d_ws, size_t ws_size,
                              hipStream_t stream) {
  const float* x1 = (const float*)d_in[0];
  const float* x2 = (const float*)d_in[1];
  const float* w  = (const float*)d_in[2];
  float* out = (float*)d_out;
  _Float16* Wh = (_Float16*)d_ws;            // 15*64*4096 f16 = 7.86 MB scratch

  const int nw = 15 * 64 * 4096;
  const int n4 = nw / 4;
  hipLaunchKernelGGL(cvt_w_kernel, dim3((n4 + 255) / 256), dim3(256), 0, stream, w, Wh, n4);

  dim3 grid(32, 13);  // 32 z-tiles x 13 output slots
  hipLaunchKernelGGL(tp_kernel, grid, dim3(256), 0, stream, x1, x2, Wh, out);
}